// Round 7
// baseline (198.546 us; speedup 1.0000x reference)
//
#include <hip/hip_runtime.h>
#include <hip/hip_bf16.h>

typedef __bf16 bf16x8 __attribute__((ext_vector_type(8)));
typedef short short8 __attribute__((ext_vector_type(8)));
typedef float f32x4 __attribute__((ext_vector_type(4)));

union BF8 { short8 s; bf16x8 b; };

#define N_NODES 4096
#define F_IN 512
#define F_OUT 64
#define NHEAD 8
#define HID 512
#define NCLS 10
#define GAT_ALPHA 0.2f
#define MSPLIT 4
#define WST 4096
#define NWORD (N_NODES / 64)
#define RB 32             // att1 rows per block
#define CB 32             // att1 staged cols per tile
#define NIT ((N_NODES / MSPLIT) / CB)   // 32

__device__ inline unsigned short f2bf(float f) {
  unsigned u = __builtin_bit_cast(unsigned, f);
  unsigned r = (u + 0x7FFFu + ((u >> 16) & 1u)) >> 16;
  return (unsigned short)r;
}
__device__ inline float bf2f(unsigned short h) {
  unsigned u = ((unsigned)h) << 16;
  return __builtin_bit_cast(float, u);
}

// ---------------- pack adjacency to bits: adjbits[n][m/64] -----------------
__global__ __launch_bounds__(256) void pack_adj_kernel(
    const int* __restrict__ adj, unsigned long long* __restrict__ bits) {
  int wid = blockIdx.x * 4 + (threadIdx.x >> 6);
  int l = threadIdx.x & 63;
  unsigned long long m = __ballot(adj[(size_t)wid * 64 + l] != 0);
  if (l == 0) bits[wid] = m;
}

// ---------------- GEMM1: WhbT bf16 + fused f1/f2 exp tables ----------------
__global__ __launch_bounds__(256) void gemm1_kernel(
    const float* __restrict__ x, const float* __restrict__ W,
    const float* __restrict__ a1, const float* __restrict__ a2,
    unsigned short* __restrict__ WhbT, float* __restrict__ rho1,
    float* __restrict__ E2, float* __restrict__ E2s) {
  __shared__ short As[64 * 40];
  __shared__ short Bs[64 * 40];
  const int bx = blockIdx.x;
  const int h  = blockIdx.y;
  const int t  = threadIdx.x;
  const int w  = t >> 6, l = t & 63;
  const int lr = l & 15, ls = l >> 4;
  f32x4 acc[4] = {};
  for (int k0 = 0; k0 < F_IN; k0 += 32) {
    {
      int r = t >> 2, c0 = (t & 3) * 8;
      const float* src = x + (bx * 64 + r) * F_IN + k0 + c0;
      float4 v0 = *(const float4*)src;
      float4 v1 = *(const float4*)(src + 4);
      short8 sv;
      sv[0]=f2bf(v0.x); sv[1]=f2bf(v0.y); sv[2]=f2bf(v0.z); sv[3]=f2bf(v0.w);
      sv[4]=f2bf(v1.x); sv[5]=f2bf(v1.y); sv[6]=f2bf(v1.z); sv[7]=f2bf(v1.w);
      *(short8*)&As[r * 40 + c0] = sv;
    }
    {
      int kk = t >> 3, o0 = (t & 7) * 8;
      const float* src = W + ((h * F_IN) + k0 + kk) * F_OUT + o0;
      float4 v0 = *(const float4*)src;
      float4 v1 = *(const float4*)(src + 4);
      float vv[8] = {v0.x, v0.y, v0.z, v0.w, v1.x, v1.y, v1.z, v1.w};
      #pragma unroll
      for (int i = 0; i < 8; ++i) Bs[(o0 + i) * 40 + kk] = f2bf(vv[i]);
    }
    __syncthreads();
    BF8 a; a.s = *(short8*)&As[(w * 16 + lr) * 40 + ls * 8];
    #pragma unroll
    for (int fc = 0; fc < 4; ++fc) {
      BF8 b; b.s = *(short8*)&Bs[(fc * 16 + lr) * 40 + ls * 8];
      acc[fc] = __builtin_amdgcn_mfma_f32_16x16x32_bf16(a.b, b.b, acc[fc], 0, 0, 0);
    }
    __syncthreads();
  }
  #pragma unroll
  for (int fc = 0; fc < 4; ++fc)
    #pragma unroll
    for (int j = 0; j < 4; ++j) {
      int row = bx * 64 + w * 16 + ls * 4 + j;   // C/D: row=(l>>4)*4+j
      int col = fc * 16 + lr;                    // C/D: col=l&15
      WhbT[(size_t)(h * F_OUT + col) * WST + row] = f2bf(acc[fc][j]);
    }
  float a1c[4], a2c[4];
  #pragma unroll
  for (int fc = 0; fc < 4; ++fc) {
    a1c[fc] = a1[h * F_OUT + fc * 16 + lr];
    a2c[fc] = a2[h * F_OUT + fc * 16 + lr];
  }
  #pragma unroll
  for (int j = 0; j < 4; ++j) {
    float s1 = 0.f, s2 = 0.f;
    #pragma unroll
    for (int fc = 0; fc < 4; ++fc) { s1 += acc[fc][j] * a1c[fc]; s2 += acc[fc][j] * a2c[fc]; }
    #pragma unroll
    for (int off = 1; off <= 8; off <<= 1) {
      s1 += __shfl_xor(s1, off, 64);
      s2 += __shfl_xor(s2, off, 64);
    }
    if (lr == 0) {
      int row = bx * 64 + w * 16 + ls * 4 + j;
      int idx = h * N_NODES + row;
      rho1[idx] = __expf((GAT_ALPHA - 1.f) * s1);
      E2[idx]   = __expf(s2);
      E2s[idx]  = __expf(GAT_ALPHA * s2);
    }
  }
}

// ---------------- ATT1: fully software-pipelined (tables 1-ahead, DMA 2-ahead)
#define LOADT(itx, sl) do {                                                   \
    const int tbL = tb0 + (itx) * CB;                                         \
    const int cbL = tbL + s * 8;                                              \
    by0[sl] = (unsigned)(ab0[tbL >> 6] >> ((tbL & 32) + s * 8)) & 0xffu;      \
    by1[sl] = (unsigned)(ab1[tbL >> 6] >> ((tbL & 32) + s * 8)) & 0xffu;      \
    ea[sl] = *(const float4*)(E2h + cbL);                                     \
    eb[sl] = *(const float4*)(E2h + cbL + 4);                                 \
    sa[sl] = *(const float4*)(E2sh + cbL);                                    \
    sb[sl] = *(const float4*)(E2sh + cbL + 4);                                \
  } while (0)

#define DMAQ(itx, buf) do {                                                   \
    const int tbD = tb0 + (itx) * CB;                                         \
    _Pragma("unroll")                                                         \
    for (int i = 0; i < 4; ++i)                                               \
      __builtin_amdgcn_global_load_lds(                                       \
        (const __attribute__((address_space(1))) void*)(gsrc0 + tbD + (size_t)(i * 16) * WST), \
        (__attribute__((address_space(3))) void*)&Bt[buf][h][i * 512], 16, 0, 0); \
  } while (0)

#define BODY(it, cur, nxt) do {                                               \
    if ((it) + 1 < NIT) LOADT((it) + 1, nxt);                                 \
    __builtin_amdgcn_sched_barrier(0);                                        \
    float ev_[8] = {ea[cur].x, ea[cur].y, ea[cur].z, ea[cur].w,               \
                    eb[cur].x, eb[cur].y, eb[cur].z, eb[cur].w};              \
    float sv_[8] = {sa[cur].x, sa[cur].y, sa[cur].z, sa[cur].w,               \
                    sb[cur].x, sb[cur].y, sb[cur].z, sb[cur].w};              \
    BF8 a0, a1f;                                                              \
    _Pragma("unroll")                                                         \
    for (int j = 0; j < 8; ++j) {                                             \
      float q0 = fmaxf(ev_[j], rho0 * sv_[j]);                                \
      q0 = ((by0[cur] >> j) & 1u) ? q0 : 0.f;                                 \
      S0 += q0; a0.b[j] = (__bf16)q0;                                         \
      float q1 = fmaxf(ev_[j], rho1v * sv_[j]);                               \
      q1 = ((by1[cur] >> j) & 1u) ? q1 : 0.f;                                 \
      S1 += q1; a1f.b[j] = (__bf16)q1;                                        \
    }                                                                         \
    if ((it) == NIT - 1) { asm volatile("s_waitcnt vmcnt(6)" ::: "memory"); } \
    else                 { asm volatile("s_waitcnt vmcnt(16)" ::: "memory"); }\
    BF8 b0, b1, b2, b3;                                                       \
    b0.s = *(short8*)&Bt[(it) & 1][h][(0 * 16 + r) * CB + ((s ^ ((r >> 1) & 3)) * 8)]; \
    b1.s = *(short8*)&Bt[(it) & 1][h][(1 * 16 + r) * CB + ((s ^ ((r >> 1) & 3)) * 8)]; \
    b2.s = *(short8*)&Bt[(it) & 1][h][(2 * 16 + r) * CB + ((s ^ ((r >> 1) & 3)) * 8)]; \
    b3.s = *(short8*)&Bt[(it) & 1][h][(3 * 16 + r) * CB + ((s ^ ((r >> 1) & 3)) * 8)]; \
    asm volatile("s_waitcnt lgkmcnt(0)" ::: "memory");                        \
    __builtin_amdgcn_sched_barrier(0);                                        \
    acc[0][0] = __builtin_amdgcn_mfma_f32_16x16x32_bf16(a0.b,  b0.b, acc[0][0], 0, 0, 0); \
    acc[0][1] = __builtin_amdgcn_mfma_f32_16x16x32_bf16(a0.b,  b1.b, acc[0][1], 0, 0, 0); \
    acc[0][2] = __builtin_amdgcn_mfma_f32_16x16x32_bf16(a0.b,  b2.b, acc[0][2], 0, 0, 0); \
    acc[0][3] = __builtin_amdgcn_mfma_f32_16x16x32_bf16(a0.b,  b3.b, acc[0][3], 0, 0, 0); \
    acc[1][0] = __builtin_amdgcn_mfma_f32_16x16x32_bf16(a1f.b, b0.b, acc[1][0], 0, 0, 0); \
    acc[1][1] = __builtin_amdgcn_mfma_f32_16x16x32_bf16(a1f.b, b1.b, acc[1][1], 0, 0, 0); \
    acc[1][2] = __builtin_amdgcn_mfma_f32_16x16x32_bf16(a1f.b, b2.b, acc[1][2], 0, 0, 0); \
    acc[1][3] = __builtin_amdgcn_mfma_f32_16x16x32_bf16(a1f.b, b3.b, acc[1][3], 0, 0, 0); \
    if ((it) + 2 < NIT) DMAQ((it) + 2, cur);                                  \
    __builtin_amdgcn_sched_barrier(0);                                        \
  } while (0)

__global__ __launch_bounds__(512, 4) void att1_kernel(
    const unsigned long long* __restrict__ adjbits,
    const float* __restrict__ rho1,
    const float* __restrict__ E2, const float* __restrict__ E2s,
    const unsigned short* __restrict__ WhbT,
    float* __restrict__ accP, float* __restrict__ SP) {
  __shared__ __align__(16) short Bt[2][NHEAD][64 * CB];   // 64 KB
  const int nb = blockIdx.x * RB;
  const int q  = blockIdx.y;
  const int t  = threadIdx.x;
  const int h  = t >> 6;               // wave = head
  const int l  = t & 63;
  const int r  = l & 15, s = l >> 4;

  const float rho0  = rho1[h * N_NODES + nb + r];
  const float rho1v = rho1[h * N_NODES + nb + 16 + r];
  const float* __restrict__ E2h  = E2  + h * N_NODES;
  const float* __restrict__ E2sh = E2s + h * N_NODES;
  const unsigned long long* __restrict__ ab0 = adjbits + (size_t)(nb + r) * NWORD;
  const unsigned long long* __restrict__ ab1 = adjbits + (size_t)(nb + 16 + r) * NWORD;

  // DMA source: lane l covers out-row (l>>2), granule (l&3), col pre-swizzled
  const unsigned short* gsrc0 =
      WhbT + (size_t)(h * F_OUT + (l >> 2)) * WST + (((l & 3) ^ ((l >> 3) & 3)) * 8);

  const int tb0 = q * (N_NODES / MSPLIT);

  float4 ea[2], eb[2], sa[2], sb[2];
  unsigned by0[2], by1[2];

  __builtin_amdgcn_sched_barrier(0);
  DMAQ(0, 0);
  __builtin_amdgcn_sched_barrier(0);
  LOADT(0, 0);
  __builtin_amdgcn_sched_barrier(0);
  DMAQ(1, 1);
  __builtin_amdgcn_sched_barrier(0);

  float S0 = 0.f, S1 = 0.f;
  f32x4 acc[2][4] = {};
  for (int i2 = 0; i2 < NIT / 2; ++i2) {
    BODY(2 * i2,     0, 1);
    BODY(2 * i2 + 1, 1, 0);
  }

  S0 += __shfl_xor(S0, 16, 64); S0 += __shfl_xor(S0, 32, 64);
  S1 += __shfl_xor(S1, 16, 64); S1 += __shfl_xor(S1, 32, 64);
  if (s == 0) {
    SP[((size_t)q * NHEAD + h) * N_NODES + nb + r]      = S0;
    SP[((size_t)q * NHEAD + h) * N_NODES + nb + 16 + r] = S1;
  }
  #pragma unroll
  for (int rg = 0; rg < 2; ++rg)
    #pragma unroll
    for (int fc = 0; fc < 4; ++fc)
      #pragma unroll
      for (int j = 0; j < 4; ++j) {
        int n = nb + rg * 16 + s * 4 + j;          // C/D: row=(l>>4)*4+j
        int col = h * F_OUT + fc * 16 + r;         // C/D: col=l&15
        accP[((size_t)q * N_NODES + n) * HID + col] = acc[rg][fc][j];
      }
}

// ---------------- ATT1 reduce: combine partials, ELU, write hcat -----------
__global__ __launch_bounds__(512) void att1_reduce_kernel(
    const float* __restrict__ accP, const float* __restrict__ SP,
    unsigned short* __restrict__ hcat) {
  const int n = blockIdx.x;
  const int c = threadIdx.x;
  const int h = c >> 6;
  float Ssum = 0.f;
  #pragma unroll
  for (int q = 0; q < MSPLIT; ++q) Ssum += SP[((size_t)q * NHEAD + h) * N_NODES + n];
  float v = 0.f;
  #pragma unroll
  for (int q = 0; q < MSPLIT; ++q) v += accP[((size_t)q * N_NODES + n) * HID + c];
  v /= Ssum;
  float e = v > 0.f ? v : (__expf(v) - 1.0f);
  hcat[(size_t)n * HID + c] = f2bf(e);
}

// ---------------- GEMM2: Wh2 = hcat @ Wo (short8 loads), rho_o/Eg2 ---------
__global__ __launch_bounds__(256) void gemm2_kernel(
    const unsigned short* __restrict__ hcat, const float* __restrict__ Wo,
    const float* __restrict__ ao1, const float* __restrict__ ao2,
    float* __restrict__ Wh2, float* __restrict__ rho_o,
    float* __restrict__ Eg2, float* __restrict__ Eg2s) {
  int n = blockIdx.x * 4 + (threadIdx.x >> 6);
  int l = threadIdx.x & 63;
  short8 hv8 = *(const short8*)&hcat[(size_t)n * HID + l * 8];
  float acc[NCLS] = {};
  #pragma unroll
  for (int j = 0; j < 8; ++j) {
    float hv = bf2f((unsigned short)hv8[j]);
    const float* wrow = Wo + (l * 8 + j) * NCLS;
    #pragma unroll
    for (int c = 0; c < NCLS; ++c) acc[c] += hv * wrow[c];
  }
  #pragma unroll
  for (int c = 0; c < NCLS; ++c)
    #pragma unroll
    for (int off = 32; off > 0; off >>= 1) acc[c] += __shfl_xor(acc[c], off, 64);
  if (l == 0) {
    float s1 = 0.f, s2 = 0.f;
    #pragma unroll
    for (int c = 0; c < NCLS; ++c) {
      Wh2[n * NCLS + c] = acc[c];
      s1 += acc[c] * ao1[c];
      s2 += acc[c] * ao2[c];
    }
    rho_o[n] = __expf((GAT_ALPHA - 1.f) * s1);
    Eg2[n]   = __expf(s2);
    Eg2s[n]  = __expf(GAT_ALPHA * s2);
  }
}

// ---------------- ATT2 + log_softmax (max-form, e1 cancels) ----------------
__global__ __launch_bounds__(256) void att2_kernel(
    const unsigned long long* __restrict__ adjbits,
    const float* __restrict__ rho_o,
    const float* __restrict__ Eg2, const float* __restrict__ Eg2s,
    const float* __restrict__ Wh2, float* __restrict__ out) {
  int n = blockIdx.x * 4 + (threadIdx.x >> 6);
  int l = threadIdx.x & 63;
  const float ro = rho_o[n];
  const unsigned long long* __restrict__ abrow = adjbits + (size_t)n * NWORD;
  float S = 0.f;
  float acc[NCLS] = {};
  for (int tb = 0; tb < N_NODES; tb += 64) {
    int m = tb + l;
    unsigned long long bits = abrow[tb >> 6];
    float qv = fmaxf(Eg2[m], ro * Eg2s[m]);
    qv = ((bits >> l) & 1ull) ? qv : 0.f;
    S += qv;
    const float* wrow = Wh2 + m * NCLS;
    #pragma unroll
    for (int c = 0; c < NCLS; ++c) acc[c] += qv * wrow[c];
  }
  #pragma unroll
  for (int off = 32; off > 0; off >>= 1) S += __shfl_xor(S, off, 64);
  #pragma unroll
  for (int c = 0; c < NCLS; ++c)
    #pragma unroll
    for (int off = 32; off > 0; off >>= 1) acc[c] += __shfl_xor(acc[c], off, 64);
  float rS = 1.0f / S;
  float lo[NCLS]; float mx = -1e30f;
  #pragma unroll
  for (int c = 0; c < NCLS; ++c) { lo[c] = acc[c] * rS; mx = fmaxf(mx, lo[c]); }
  float se = 0.f;
  #pragma unroll
  for (int c = 0; c < NCLS; ++c) se += __expf(lo[c] - mx);
  float lse = mx + __logf(se);
  if (l == 0) {
    #pragma unroll
    for (int c = 0; c < NCLS; ++c) out[n * NCLS + c] = lo[c] - lse;
  }
}

extern "C" void kernel_launch(void* const* d_in, const int* in_sizes, int n_in,
                              void* d_out, int out_size, void* d_ws, size_t ws_size,
                              hipStream_t stream) {
  (void)in_sizes; (void)n_in; (void)out_size; (void)ws_size;
  const float* x   = (const float*)d_in[0];
  const int*   adj = (const int*)d_in[1];
  const float* W   = (const float*)d_in[2];
  const float* a1  = (const float*)d_in[3];
  const float* a2  = (const float*)d_in[4];
  const float* Wo  = (const float*)d_in[5];
  const float* ao1 = (const float*)d_in[6];
  const float* ao2 = (const float*)d_in[7];
  float* out = (float*)d_out;

  char* ws = (char*)d_ws;
  unsigned long long* adjbits = (unsigned long long*)ws; ws += (size_t)N_NODES * NWORD * 8;
  unsigned short* WhbT= (unsigned short*)ws; ws += (size_t)HID * WST * 2;
  unsigned short* hcat= (unsigned short*)ws; ws += (size_t)N_NODES * HID * 2;
  float* accP         = (float*)ws;          ws += (size_t)MSPLIT * N_NODES * HID * 4;
  float* SP           = (float*)ws;          ws += (size_t)MSPLIT * NHEAD * N_NODES * 4;
  float* rho1         = (float*)ws;          ws += (size_t)NHEAD * N_NODES * 4;
  float* E2           = (float*)ws;          ws += (size_t)NHEAD * N_NODES * 4;
  float* E2s          = (float*)ws;          ws += (size_t)NHEAD * N_NODES * 4;
  float* Wh2          = (float*)ws;          ws += (size_t)N_NODES * NCLS * 4;
  float* rho_o        = (float*)ws;          ws += (size_t)N_NODES * 4;
  float* Eg2          = (float*)ws;          ws += (size_t)N_NODES * 4;
  float* Eg2s         = (float*)ws;          ws += (size_t)N_NODES * 4;

  pack_adj_kernel<<<N_NODES * NWORD / 4, 256, 0, stream>>>(adj, adjbits);
  gemm1_kernel<<<dim3(64, 8), 256, 0, stream>>>(x, W, a1, a2, WhbT, rho1, E2, E2s);
  att1_kernel<<<dim3(N_NODES / RB, MSPLIT), 512, 0, stream>>>(adjbits, rho1, E2, E2s, WhbT, accP, SP);
  att1_reduce_kernel<<<N_NODES, 512, 0, stream>>>(accP, SP, hcat);
  gemm2_kernel<<<N_NODES / 4, 256, 0, stream>>>(hcat, Wo, ao1, ao2, Wh2, rho_o, Eg2, Eg2s);
  att2_kernel<<<N_NODES / 4, 256, 0, stream>>>(adjbits, rho_o, Eg2, Eg2s, Wh2, out);
}

// Round 8
// 166.936 us; speedup vs baseline: 1.1894x; 1.1894x over previous
//
#include <hip/hip_runtime.h>
#include <hip/hip_bf16.h>

typedef __bf16 bf16x8 __attribute__((ext_vector_type(8)));
typedef short short8 __attribute__((ext_vector_type(8)));
typedef float f32x4 __attribute__((ext_vector_type(4)));

union BF8 { short8 s; bf16x8 b; };

#define N_NODES 4096
#define F_IN 512
#define F_OUT 64
#define NHEAD 8
#define HID 512
#define NCLS 10
#define GAT_ALPHA 0.2f
#define MSPLIT 4
#define WST 4096
#define NWORD (N_NODES / 64)
#define RB 32             // att1 rows per block
#define CB 64             // att1 staged cols per tile (r5's amortization)
#define NIT ((N_NODES / MSPLIT) / CB)   // 16

__device__ inline unsigned short f2bf(float f) {
  unsigned u = __builtin_bit_cast(unsigned, f);
  unsigned r = (u + 0x7FFFu + ((u >> 16) & 1u)) >> 16;
  return (unsigned short)r;
}
__device__ inline float bf2f(unsigned short h) {
  unsigned u = ((unsigned)h) << 16;
  return __builtin_bit_cast(float, u);
}

// ---------------- pack adjacency to bits: adjbits[n][m/64] -----------------
__global__ __launch_bounds__(256) void pack_adj_kernel(
    const int* __restrict__ adj, unsigned long long* __restrict__ bits) {
  int wid = blockIdx.x * 4 + (threadIdx.x >> 6);
  int l = threadIdx.x & 63;
  unsigned long long m = __ballot(adj[(size_t)wid * 64 + l] != 0);
  if (l == 0) bits[wid] = m;
}

// ---------------- GEMM1: WhbT bf16 + fused f1/f2 exp tables ----------------
__global__ __launch_bounds__(256) void gemm1_kernel(
    const float* __restrict__ x, const float* __restrict__ W,
    const float* __restrict__ a1, const float* __restrict__ a2,
    unsigned short* __restrict__ WhbT, float* __restrict__ rho1,
    float* __restrict__ E2, float* __restrict__ E2s) {
  __shared__ short As[64 * 40];
  __shared__ short Bs[64 * 40];
  const int bx = blockIdx.x;
  const int h  = blockIdx.y;
  const int t  = threadIdx.x;
  const int w  = t >> 6, l = t & 63;
  const int lr = l & 15, ls = l >> 4;
  f32x4 acc[4] = {};
  for (int k0 = 0; k0 < F_IN; k0 += 32) {
    {
      int r = t >> 2, c0 = (t & 3) * 8;
      const float* src = x + (bx * 64 + r) * F_IN + k0 + c0;
      float4 v0 = *(const float4*)src;
      float4 v1 = *(const float4*)(src + 4);
      short8 sv;
      sv[0]=f2bf(v0.x); sv[1]=f2bf(v0.y); sv[2]=f2bf(v0.z); sv[3]=f2bf(v0.w);
      sv[4]=f2bf(v1.x); sv[5]=f2bf(v1.y); sv[6]=f2bf(v1.z); sv[7]=f2bf(v1.w);
      *(short8*)&As[r * 40 + c0] = sv;
    }
    {
      int kk = t >> 3, o0 = (t & 7) * 8;
      const float* src = W + ((h * F_IN) + k0 + kk) * F_OUT + o0;
      float4 v0 = *(const float4*)src;
      float4 v1 = *(const float4*)(src + 4);
      float vv[8] = {v0.x, v0.y, v0.z, v0.w, v1.x, v1.y, v1.z, v1.w};
      #pragma unroll
      for (int i = 0; i < 8; ++i) Bs[(o0 + i) * 40 + kk] = f2bf(vv[i]);
    }
    __syncthreads();
    BF8 a; a.s = *(short8*)&As[(w * 16 + lr) * 40 + ls * 8];
    #pragma unroll
    for (int fc = 0; fc < 4; ++fc) {
      BF8 b; b.s = *(short8*)&Bs[(fc * 16 + lr) * 40 + ls * 8];
      acc[fc] = __builtin_amdgcn_mfma_f32_16x16x32_bf16(a.b, b.b, acc[fc], 0, 0, 0);
    }
    __syncthreads();
  }
  #pragma unroll
  for (int fc = 0; fc < 4; ++fc)
    #pragma unroll
    for (int j = 0; j < 4; ++j) {
      int row = bx * 64 + w * 16 + ls * 4 + j;   // C/D: row=(l>>4)*4+j
      int col = fc * 16 + lr;                    // C/D: col=l&15
      WhbT[(size_t)(h * F_OUT + col) * WST + row] = f2bf(acc[fc][j]);
    }
  float a1c[4], a2c[4];
  #pragma unroll
  for (int fc = 0; fc < 4; ++fc) {
    a1c[fc] = a1[h * F_OUT + fc * 16 + lr];
    a2c[fc] = a2[h * F_OUT + fc * 16 + lr];
  }
  #pragma unroll
  for (int j = 0; j < 4; ++j) {
    float s1 = 0.f, s2 = 0.f;
    #pragma unroll
    for (int fc = 0; fc < 4; ++fc) { s1 += acc[fc][j] * a1c[fc]; s2 += acc[fc][j] * a2c[fc]; }
    #pragma unroll
    for (int off = 1; off <= 8; off <<= 1) {
      s1 += __shfl_xor(s1, off, 64);
      s2 += __shfl_xor(s2, off, 64);
    }
    if (lr == 0) {
      int row = bx * 64 + w * 16 + ls * 4 + j;
      int idx = h * N_NODES + row;
      rho1[idx] = __expf((GAT_ALPHA - 1.f) * s1);
      E2[idx]   = __expf(s2);
      E2s[idx]  = __expf(GAT_ALPHA * s2);
    }
  }
}

// ---------------- ATT1: r5 synchronous structure, 64KB LDS, 4 waves/SIMD ---
// wave = head, fully wave-private LDS region, no __syncthreads.
// Invariant (r5): table loads for tile it are issued AFTER the DMA that must
// complete before tile it's MFMA — the compiler's consume-wait (in-order
// vmcnt drain) then covers the DMA for free.
__global__ __launch_bounds__(512, 4) void att1_kernel(
    const unsigned long long* __restrict__ adjbits,
    const float* __restrict__ rho1,
    const float* __restrict__ E2, const float* __restrict__ E2s,
    const unsigned short* __restrict__ WhbT,
    float* __restrict__ accP, float* __restrict__ SP) {
  __shared__ __align__(16) short Bt[NHEAD][64 * CB];   // 64 KB single buffer
  const int nb = blockIdx.x * RB;
  const int q  = blockIdx.y;
  const int t  = threadIdx.x;
  const int h  = t >> 6;               // wave = head
  const int l  = t & 63;
  const int r  = l & 15, s = l >> 4;

  const float rho0  = rho1[h * N_NODES + nb + r];
  const float rho1v = rho1[h * N_NODES + nb + 16 + r];
  const float* __restrict__ E2h  = E2  + h * N_NODES;
  const float* __restrict__ E2sh = E2s + h * N_NODES;
  const unsigned long long* __restrict__ ab0 = adjbits + (size_t)(nb + r) * NWORD;
  const unsigned long long* __restrict__ ab1 = adjbits + (size_t)(nb + 16 + r) * NWORD;

  // DMA source (verbatim r5 mapping): lane l covers out-row (l>>3) of each
  // 8-row octet, source col granule pre-swizzled by (l>>3) -> 2-way banks.
  const unsigned short* gsrc0 =
      WhbT + (size_t)(h * F_OUT + (l >> 3)) * WST + (((l & 7) ^ (l >> 3)) * 8);

  const int tb0 = q * (N_NODES / MSPLIT);

  // prologue: stage tile 0
  #pragma unroll
  for (int i = 0; i < 8; ++i)
    __builtin_amdgcn_global_load_lds(
        (const __attribute__((address_space(1))) void*)(gsrc0 + tb0 + (size_t)(i * 8) * WST),
        (__attribute__((address_space(3))) void*)&Bt[h][i * 512], 16, 0, 0);

  float S0 = 0.f, S1 = 0.f;
  f32x4 acc[2][4] = {};
  for (int it = 0; it < NIT; ++it) {
    const int tb = tb0 + it * CB;
    // adj + tables for tile it (issued after DMA(it); consume-wait drains it)
    const unsigned long long mk0 = ab0[tb >> 6];
    const unsigned long long mk1 = ab1[tb >> 6];
    BF8 a0[2], a1f[2];
    #pragma unroll
    for (int kf = 0; kf < 2; ++kf) {
      const int cb = tb + kf * 32 + s * 8;
      float4 ea = *(const float4*)(E2h + cb);
      float4 eb = *(const float4*)(E2h + cb + 4);
      float4 sa = *(const float4*)(E2sh + cb);
      float4 sb = *(const float4*)(E2sh + cb + 4);
      float ev[8] = {ea.x, ea.y, ea.z, ea.w, eb.x, eb.y, eb.z, eb.w};
      float sv[8] = {sa.x, sa.y, sa.z, sa.w, sb.x, sb.y, sb.z, sb.w};
      const unsigned b0m = (unsigned)(mk0 >> (kf * 32 + s * 8)) & 0xffu;
      const unsigned b1m = (unsigned)(mk1 >> (kf * 32 + s * 8)) & 0xffu;
      #pragma unroll
      for (int j = 0; j < 8; ++j) {
        float q0 = fmaxf(ev[j], rho0 * sv[j]);
        q0 = ((b0m >> j) & 1u) ? q0 : 0.f;
        S0 += q0; a0[kf].b[j] = (__bf16)q0;
        float q1 = fmaxf(ev[j], rho1v * sv[j]);
        q1 = ((b1m >> j) & 1u) ? q1 : 0.f;
        S1 += q1; a1f[kf].b[j] = (__bf16)q1;
      }
    }
    // DMA(it) complete (already drained by table consume; explicit for safety)
    asm volatile("s_waitcnt vmcnt(0)" ::: "memory");
    // B fragments LDS -> registers, then buffer is free
    BF8 b[2][4];
    #pragma unroll
    for (int kf = 0; kf < 2; ++kf)
      #pragma unroll
      for (int fc = 0; fc < 4; ++fc)
        b[kf][fc].s = *(short8*)&Bt[h][(fc * 16 + r) * CB + ((kf * 32 + s * 8) ^ ((r & 7) * 8))];
    asm volatile("s_waitcnt lgkmcnt(0)" ::: "memory");
    __builtin_amdgcn_sched_barrier(0);
    // WAR-safe: stage tile it+1 into the (now register-copied) buffer
    if (it + 1 < NIT) {
      #pragma unroll
      for (int i = 0; i < 8; ++i)
        __builtin_amdgcn_global_load_lds(
            (const __attribute__((address_space(1))) void*)(gsrc0 + tb + CB + (size_t)(i * 8) * WST),
            (__attribute__((address_space(3))) void*)&Bt[h][i * 512], 16, 0, 0);
    }
    __builtin_amdgcn_sched_barrier(0);
    #pragma unroll
    for (int kf = 0; kf < 2; ++kf)
      #pragma unroll
      for (int fc = 0; fc < 4; ++fc) {
        acc[0][fc] = __builtin_amdgcn_mfma_f32_16x16x32_bf16(a0[kf].b,  b[kf][fc].b, acc[0][fc], 0, 0, 0);
        acc[1][fc] = __builtin_amdgcn_mfma_f32_16x16x32_bf16(a1f[kf].b, b[kf][fc].b, acc[1][fc], 0, 0, 0);
      }
  }

  S0 += __shfl_xor(S0, 16, 64); S0 += __shfl_xor(S0, 32, 64);
  S1 += __shfl_xor(S1, 16, 64); S1 += __shfl_xor(S1, 32, 64);
  if (s == 0) {
    SP[((size_t)q * NHEAD + h) * N_NODES + nb + r]      = S0;
    SP[((size_t)q * NHEAD + h) * N_NODES + nb + 16 + r] = S1;
  }
  #pragma unroll
  for (int rg = 0; rg < 2; ++rg)
    #pragma unroll
    for (int fc = 0; fc < 4; ++fc)
      #pragma unroll
      for (int j = 0; j < 4; ++j) {
        int n = nb + rg * 16 + s * 4 + j;          // C/D: row=(l>>4)*4+j
        int col = h * F_OUT + fc * 16 + r;         // C/D: col=l&15
        accP[((size_t)q * N_NODES + n) * HID + col] = acc[rg][fc][j];
      }
}

// ---------------- ATT1 reduce: combine partials, ELU, write hcat -----------
__global__ __launch_bounds__(512) void att1_reduce_kernel(
    const float* __restrict__ accP, const float* __restrict__ SP,
    unsigned short* __restrict__ hcat) {
  const int n = blockIdx.x;
  const int c = threadIdx.x;
  const int h = c >> 6;
  float Ssum = 0.f;
  #pragma unroll
  for (int q = 0; q < MSPLIT; ++q) Ssum += SP[((size_t)q * NHEAD + h) * N_NODES + n];
  float v = 0.f;
  #pragma unroll
  for (int q = 0; q < MSPLIT; ++q) v += accP[((size_t)q * N_NODES + n) * HID + c];
  v /= Ssum;
  float e = v > 0.f ? v : (__expf(v) - 1.0f);
  hcat[(size_t)n * HID + c] = f2bf(e);
}

// ---------------- GEMM2: Wh2 = hcat @ Wo (short8 loads), rho_o/Eg2 ---------
__global__ __launch_bounds__(256) void gemm2_kernel(
    const unsigned short* __restrict__ hcat, const float* __restrict__ Wo,
    const float* __restrict__ ao1, const float* __restrict__ ao2,
    float* __restrict__ Wh2, float* __restrict__ rho_o,
    float* __restrict__ Eg2, float* __restrict__ Eg2s) {
  int n = blockIdx.x * 4 + (threadIdx.x >> 6);
  int l = threadIdx.x & 63;
  short8 hv8 = *(const short8*)&hcat[(size_t)n * HID + l * 8];
  float acc[NCLS] = {};
  #pragma unroll
  for (int j = 0; j < 8; ++j) {
    float hv = bf2f((unsigned short)hv8[j]);
    const float* wrow = Wo + (l * 8 + j) * NCLS;
    #pragma unroll
    for (int c = 0; c < NCLS; ++c) acc[c] += hv * wrow[c];
  }
  #pragma unroll
  for (int c = 0; c < NCLS; ++c)
    #pragma unroll
    for (int off = 32; off > 0; off >>= 1) acc[c] += __shfl_xor(acc[c], off, 64);
  if (l == 0) {
    float s1 = 0.f, s2 = 0.f;
    #pragma unroll
    for (int c = 0; c < NCLS; ++c) {
      Wh2[n * NCLS + c] = acc[c];
      s1 += acc[c] * ao1[c];
      s2 += acc[c] * ao2[c];
    }
    rho_o[n] = __expf((GAT_ALPHA - 1.f) * s1);
    Eg2[n]   = __expf(s2);
    Eg2s[n]  = __expf(GAT_ALPHA * s2);
  }
}

// ---------------- ATT2 + log_softmax (max-form, e1 cancels) ----------------
__global__ __launch_bounds__(256) void att2_kernel(
    const unsigned long long* __restrict__ adjbits,
    const float* __restrict__ rho_o,
    const float* __restrict__ Eg2, const float* __restrict__ Eg2s,
    const float* __restrict__ Wh2, float* __restrict__ out) {
  int n = blockIdx.x * 4 + (threadIdx.x >> 6);
  int l = threadIdx.x & 63;
  const float ro = rho_o[n];
  const unsigned long long* __restrict__ abrow = adjbits + (size_t)n * NWORD;
  float S = 0.f;
  float acc[NCLS] = {};
  for (int tb = 0; tb < N_NODES; tb += 64) {
    int m = tb + l;
    unsigned long long bits = abrow[tb >> 6];
    float qv = fmaxf(Eg2[m], ro * Eg2s[m]);
    qv = ((bits >> l) & 1ull) ? qv : 0.f;
    S += qv;
    const float* wrow = Wh2 + m * NCLS;
    #pragma unroll
    for (int c = 0; c < NCLS; ++c) acc[c] += qv * wrow[c];
  }
  #pragma unroll
  for (int off = 32; off > 0; off >>= 1) S += __shfl_xor(S, off, 64);
  #pragma unroll
  for (int c = 0; c < NCLS; ++c)
    #pragma unroll
    for (int off = 32; off > 0; off >>= 1) acc[c] += __shfl_xor(acc[c], off, 64);
  float rS = 1.0f / S;
  float lo[NCLS]; float mx = -1e30f;
  #pragma unroll
  for (int c = 0; c < NCLS; ++c) { lo[c] = acc[c] * rS; mx = fmaxf(mx, lo[c]); }
  float se = 0.f;
  #pragma unroll
  for (int c = 0; c < NCLS; ++c) se += __expf(lo[c] - mx);
  float lse = mx + __logf(se);
  if (l == 0) {
    #pragma unroll
    for (int c = 0; c < NCLS; ++c) out[n * NCLS + c] = lo[c] - lse;
  }
}

extern "C" void kernel_launch(void* const* d_in, const int* in_sizes, int n_in,
                              void* d_out, int out_size, void* d_ws, size_t ws_size,
                              hipStream_t stream) {
  (void)in_sizes; (void)n_in; (void)out_size; (void)ws_size;
  const float* x   = (const float*)d_in[0];
  const int*   adj = (const int*)d_in[1];
  const float* W   = (const float*)d_in[2];
  const float* a1  = (const float*)d_in[3];
  const float* a2  = (const float*)d_in[4];
  const float* Wo  = (const float*)d_in[5];
  const float* ao1 = (const float*)d_in[6];
  const float* ao2 = (const float*)d_in[7];
  float* out = (float*)d_out;

  char* ws = (char*)d_ws;
  unsigned long long* adjbits = (unsigned long long*)ws; ws += (size_t)N_NODES * NWORD * 8;
  unsigned short* WhbT= (unsigned short*)ws; ws += (size_t)HID * WST * 2;
  unsigned short* hcat= (unsigned short*)ws; ws += (size_t)N_NODES * HID * 2;
  float* accP         = (float*)ws;          ws += (size_t)MSPLIT * N_NODES * HID * 4;
  float* SP           = (float*)ws;          ws += (size_t)MSPLIT * NHEAD * N_NODES * 4;
  float* rho1         = (float*)ws;          ws += (size_t)NHEAD * N_NODES * 4;
  float* E2           = (float*)ws;          ws += (size_t)NHEAD * N_NODES * 4;
  float* E2s          = (float*)ws;          ws += (size_t)NHEAD * N_NODES * 4;
  float* Wh2          = (float*)ws;          ws += (size_t)N_NODES * NCLS * 4;
  float* rho_o        = (float*)ws;          ws += (size_t)N_NODES * 4;
  float* Eg2          = (float*)ws;          ws += (size_t)N_NODES * 4;
  float* Eg2s         = (float*)ws;          ws += (size_t)N_NODES * 4;

  pack_adj_kernel<<<N_NODES * NWORD / 4, 256, 0, stream>>>(adj, adjbits);
  gemm1_kernel<<<dim3(64, 8), 256, 0, stream>>>(x, W, a1, a2, WhbT, rho1, E2, E2s);
  att1_kernel<<<dim3(N_NODES / RB, MSPLIT), 512, 0, stream>>>(adjbits, rho1, E2, E2s, WhbT, accP, SP);
  att1_reduce_kernel<<<N_NODES, 512, 0, stream>>>(accP, SP, hcat);
  gemm2_kernel<<<N_NODES / 4, 256, 0, stream>>>(hcat, Wo, ao1, ao2, Wh2, rho_o, Eg2, Eg2s);
  att2_kernel<<<N_NODES / 4, 256, 0, stream>>>(adjbits, rho_o, Eg2, Eg2s, Wh2, out);
}